// Round 7
// baseline (867.110 us; speedup 1.0000x reference)
//
#include <hip/hip_runtime.h>
#include <math.h>

#define DD 128
#define NBKT 391          // buckets = dst>>7, dst < 50000 -> 0..390
#define P1CHUNK 4096      // edges per block in pass 1
#define P2CAP 8192        // max edges per bucket held in LDS (mean 4096, sigma 64)

// ---------------- generic zero ----------------

__global__ __launch_bounds__(256) void fill_zero_i(int* p, int n) {
    int i = blockIdx.x * 256 + threadIdx.x;
    if (i < n) p[i] = 0;
}

// ---------------- pass 1a: per-bucket global histogram (LDS-staged) ----------------

__global__ __launch_bounds__(512) void p1hist_k(const int* __restrict__ dst, int* __restrict__ gcount, int E) {
    __shared__ int lh[NBKT];
    const int tid = threadIdx.x;
    for (int i = tid; i < NBKT; i += 512) lh[i] = 0;
    __syncthreads();
    const int blk0 = blockIdx.x * P1CHUNK;
    const int blkE = min(blk0 + P1CHUNK, E);
    int i0 = blk0 + tid * 8;
    if (i0 + 8 <= blkE) {
        int4 d0 = *reinterpret_cast<const int4*>(dst + i0);
        int4 d1 = *reinterpret_cast<const int4*>(dst + i0 + 4);
        atomicAdd(&lh[d0.x >> 7], 1); atomicAdd(&lh[d0.y >> 7], 1);
        atomicAdd(&lh[d0.z >> 7], 1); atomicAdd(&lh[d0.w >> 7], 1);
        atomicAdd(&lh[d1.x >> 7], 1); atomicAdd(&lh[d1.y >> 7], 1);
        atomicAdd(&lh[d1.z >> 7], 1); atomicAdd(&lh[d1.w >> 7], 1);
    } else {
        for (int j = 0; j < 8; ++j) {
            int i = i0 + j;
            if (i < blkE) atomicAdd(&lh[dst[i] >> 7], 1);
        }
    }
    __syncthreads();
    for (int i = tid; i < NBKT; i += 512)
        if (lh[i]) atomicAdd(&gcount[i], lh[i]);
}

// ---------------- pass 1b: exclusive scan of 392 bucket counts ----------------

__global__ __launch_bounds__(512) void p1scan_k(const int* __restrict__ gcount, int* __restrict__ bbase,
                                                int* __restrict__ bcur, int E) {
    __shared__ int tmp[512];
    int t = threadIdx.x;
    int v = (t < NBKT) ? gcount[t] : 0;
    tmp[t] = v;
    __syncthreads();
#pragma unroll
    for (int o = 1; o < 512; o <<= 1) {
        int add = (t >= o) ? tmp[t - o] : 0;
        __syncthreads();
        tmp[t] += add;
        __syncthreads();
    }
    if (t <= NBKT) {
        int ex = (t < NBKT) ? (tmp[t] - v) : E;  // t == NBKT -> total = E
        bbase[t] = ex;
        if (t < NBKT) bcur[t] = ex;
    }
}

// ---------------- pass 1c: bucket-binned scatter (LDS-staged, coalesced-run writes) ----------------

__global__ __launch_bounds__(512) void p1scatter_k(const int* __restrict__ src, const int* __restrict__ dst,
                                                   int* __restrict__ bcur, int2* __restrict__ bufA, int E) {
    __shared__ int lcnt[NBKT];     // per-bucket count in this block
    __shared__ int lstart[512];    // exclusive scan (padded)
    __shared__ int blkb[NBKT];     // this block's global base per bucket
    __shared__ int2 stage[P1CHUNK];
    const int tid = threadIdx.x;
    for (int i = tid; i < NBKT; i += 512) lcnt[i] = 0;
    __syncthreads();
    const int blk0 = blockIdx.x * P1CHUNK;
    const int blkE = min(blk0 + P1CHUNK, E);
    const int i0 = blk0 + tid * 8;

    int sv[8], dv[8], bn[8], rk[8], cntT = 0;
    if (i0 + 8 <= blkE) {
        int4 s0 = *reinterpret_cast<const int4*>(src + i0);
        int4 s1 = *reinterpret_cast<const int4*>(src + i0 + 4);
        int4 d0 = *reinterpret_cast<const int4*>(dst + i0);
        int4 d1 = *reinterpret_cast<const int4*>(dst + i0 + 4);
        sv[0] = s0.x; sv[1] = s0.y; sv[2] = s0.z; sv[3] = s0.w;
        sv[4] = s1.x; sv[5] = s1.y; sv[6] = s1.z; sv[7] = s1.w;
        dv[0] = d0.x; dv[1] = d0.y; dv[2] = d0.z; dv[3] = d0.w;
        dv[4] = d1.x; dv[5] = d1.y; dv[6] = d1.z; dv[7] = d1.w;
        cntT = 8;
    } else {
#pragma unroll
        for (int j = 0; j < 8; ++j) {
            int i = i0 + j;
            if (i < blkE) { sv[j] = src[i]; dv[j] = dst[i]; cntT = j + 1; }
        }
    }
#pragma unroll
    for (int j = 0; j < 8; ++j) {
        if (j < cntT) {
            bn[j] = dv[j] >> 7;
            rk[j] = atomicAdd(&lcnt[bn[j]], 1);
        }
    }
    __syncthreads();
    // exclusive scan lcnt -> lstart (Hillis-Steele over padded 512)
    int v = (tid < NBKT) ? lcnt[tid] : 0;
    lstart[tid] = v;
    __syncthreads();
#pragma unroll
    for (int o = 1; o < 512; o <<= 1) {
        int add = (tid >= o) ? lstart[tid - o] : 0;
        __syncthreads();
        lstart[tid] += add;
        __syncthreads();
    }
    lstart[tid] -= v;  // exclusive
    __syncthreads();
    // reserve global ranges
    for (int i = tid; i < NBKT; i += 512)
        blkb[i] = lcnt[i] ? atomicAdd(&bcur[i], lcnt[i]) : 0;
    // stage into LDS ordered by bucket
#pragma unroll
    for (int j = 0; j < 8; ++j) {
        if (j < cntT) {
            int pos = lstart[bn[j]] + rk[j];
            stage[pos] = make_int2(sv[j], dv[j]);
        }
    }
    __syncthreads();
    // linear write-out: consecutive j within a bucket-run -> consecutive global
    const int cnt = blkE - blk0;
    for (int j = tid; j < cnt; j += 512) {
        int2 e = stage[j];
        int b = e.y >> 7;
        bufA[blkb[b] + (j - lstart[b])] = e;
    }
}

// ---------------- pass 2: per-bucket LDS counting sort by dst&127 ----------------

__global__ __launch_bounds__(512) void p2sort_k(const int2* __restrict__ bufA, const int* __restrict__ bbase,
                                                int* __restrict__ srcs, int* __restrict__ dstS) {
    __shared__ int h2[128];
    __shared__ int start2[128];
    __shared__ int cur2[128];
    __shared__ int ssrc[P2CAP];
    __shared__ int sdst[P2CAP];
    const int tid = threadIdx.x;
    const int b = blockIdx.x;
    const int base = bbase[b];
    const int cnt = bbase[b + 1] - base;
    for (int i = tid; i < 128; i += 512) h2[i] = 0;
    __syncthreads();
    for (int j = tid; j < cnt; j += 512)
        atomicAdd(&h2[bufA[base + j].y & 127], 1);
    __syncthreads();
    if (tid == 0) {
        int s = 0;
        for (int i = 0; i < 128; ++i) { start2[i] = s; cur2[i] = s; s += h2[i]; }
    }
    __syncthreads();
    for (int j = tid; j < cnt; j += 512) {
        int2 e = bufA[base + j];
        int p = atomicAdd(&cur2[e.y & 127], 1);
        ssrc[p] = e.x;
        sdst[p] = e.y;
    }
    __syncthreads();
    for (int j = tid; j < cnt; j += 512) {
        srcs[base + j] = ssrc[j];
        dstS[base + j] = sdst[j];
    }
}

// ---------------- CSR offsets from sorted dst (boundary detection) ----------------

__global__ __launch_bounds__(512) void off_k(const int* __restrict__ dstS, int* __restrict__ off, int N, int E) {
    int i = blockIdx.x * 512 + threadIdx.x;
    if (i >= E) return;
    int d = dstS[i];
    int p = (i == 0) ? -1 : dstS[i - 1];
    if (d != p)
        for (int n = p + 1; n <= d; ++n) off[n] = i;
    if (i == E - 1)
        for (int n = d + 1; n <= N; ++n) off[n] = E;
}

// ---------------- GEMM: Zb = blocked(X @ W^T + b), fused attn halves ----------------
// Zb layout: Zb[c][node][16] for c = 0..7 (columns 16c..16c+15) -> per-slice
// footprint 3.2 MB, L2-resident on one XCD during aggregation.

__global__ __launch_bounds__(256) void gemm_k(const float* __restrict__ X, const float* __restrict__ W,
                                              const float* __restrict__ B, const float* __restrict__ aW,
                                              float* __restrict__ Zb, float* __restrict__ a_src,
                                              float* __restrict__ a_dst, int N) {
    __shared__ __align__(16) float xs[32][64];   // transposed x chunk: xs[k][r]
    __shared__ __align__(16) float ws[32][128];  // transposed w chunk: ws[k][o]
    const int tid = threadIdx.x;
    const int row0 = blockIdx.x * 64;
    const int cg = tid & 31;  // 32 col groups of 4 cols
    const int rg = tid >> 5;  // 8 row groups of 8 rows
    float acc[8][4];
#pragma unroll
    for (int i = 0; i < 8; ++i)
#pragma unroll
        for (int j = 0; j < 4; ++j) acc[i][j] = 0.f;

    for (int kc = 0; kc < DD; kc += 32) {
        {
            int r = tid >> 2;
            int k4 = (tid & 3) * 8;
            int gr = row0 + r;
            if (gr >= N) gr = N - 1;
            const float4* p = reinterpret_cast<const float4*>(X + (size_t)gr * DD + kc + k4);
            float4 v0 = p[0], v1 = p[1];
            xs[k4 + 0][r] = v0.x; xs[k4 + 1][r] = v0.y; xs[k4 + 2][r] = v0.z; xs[k4 + 3][r] = v0.w;
            xs[k4 + 4][r] = v1.x; xs[k4 + 5][r] = v1.y; xs[k4 + 6][r] = v1.z; xs[k4 + 7][r] = v1.w;
        }
        {
            int o = tid >> 1;
            int k8 = (tid & 1) * 16;
            const float4* p = reinterpret_cast<const float4*>(W + (size_t)o * DD + kc + k8);
            float4 v0 = p[0], v1 = p[1], v2 = p[2], v3 = p[3];
            ws[k8 + 0][o] = v0.x;  ws[k8 + 1][o] = v0.y;  ws[k8 + 2][o] = v0.z;  ws[k8 + 3][o] = v0.w;
            ws[k8 + 4][o] = v1.x;  ws[k8 + 5][o] = v1.y;  ws[k8 + 6][o] = v1.z;  ws[k8 + 7][o] = v1.w;
            ws[k8 + 8][o] = v2.x;  ws[k8 + 9][o] = v2.y;  ws[k8 + 10][o] = v2.z; ws[k8 + 11][o] = v2.w;
            ws[k8 + 12][o] = v3.x; ws[k8 + 13][o] = v3.y; ws[k8 + 14][o] = v3.z; ws[k8 + 15][o] = v3.w;
        }
        __syncthreads();
#pragma unroll
        for (int k = 0; k < 32; ++k) {
            const float4 wv = *reinterpret_cast<const float4*>(&ws[k][cg * 4]);
            const float4 xa = *reinterpret_cast<const float4*>(&xs[k][rg * 8]);
            const float4 xb = *reinterpret_cast<const float4*>(&xs[k][rg * 8 + 4]);
            float xr[8] = {xa.x, xa.y, xa.z, xa.w, xb.x, xb.y, xb.z, xb.w};
            float wr[4] = {wv.x, wv.y, wv.z, wv.w};
#pragma unroll
            for (int i = 0; i < 8; ++i)
#pragma unroll
                for (int j = 0; j < 4; ++j)
                    acc[i][j] = fmaf(xr[i], wr[j], acc[i][j]);
        }
        __syncthreads();
    }
    const int c0 = cg * 4;
    const float4 bv = *reinterpret_cast<const float4*>(B + c0);
    const float4 aw0 = *reinterpret_cast<const float4*>(aW + c0);
    const float4 aw1 = *reinterpret_cast<const float4*>(aW + DD + c0);
    float pa[8], pb[8];
#pragma unroll
    for (int i = 0; i < 8; ++i) {
        acc[i][0] += bv.x; acc[i][1] += bv.y; acc[i][2] += bv.z; acc[i][3] += bv.w;
        pa[i] = acc[i][0] * aw0.x + acc[i][1] * aw0.y + acc[i][2] * aw0.z + acc[i][3] * aw0.w;
        pb[i] = acc[i][0] * aw1.x + acc[i][1] * aw1.y + acc[i][2] * aw1.z + acc[i][3] * aw1.w;
    }
#pragma unroll
    for (int o = 1; o < 32; o <<= 1) {
#pragma unroll
        for (int i = 0; i < 8; ++i) {
            pa[i] += __shfl_xor(pa[i], o);
            pb[i] += __shfl_xor(pb[i], o);
        }
    }
    const int cblk = c0 >> 4;   // feature slice 0..7
    const int cin = c0 & 15;    // column within slice
#pragma unroll
    for (int i = 0; i < 8; ++i) {
        int gr = row0 + rg * 8 + i;
        if (gr < N) {
            *reinterpret_cast<float4*>(Zb + ((size_t)cblk * N + gr) * 16 + cin) =
                *reinterpret_cast<const float4*>(&acc[i][0]);
            if (cg == 0) {
                a_src[gr] = pa[i];
                a_dst[gr] = pb[i];
            }
        }
    }
}

// ---------------- per-dst-node segment softmax + weighted aggregation ----------------
// XCD feature-sharding: slice = blockIdx%8 -> XCD via round-robin dispatch; each
// slice gathers only from its 3.2MB Zb block (L2-resident). Wave = 4 edge-groups
// x 16 col-lanes; unroll-2 per group. srcs via nontemporal loads, H via
// nontemporal stores to keep Zb hot in L2. No float atomics.

__global__ __launch_bounds__(256) void aggr_k(const float* __restrict__ Zb, const float* __restrict__ a_src,
                                              const float* __restrict__ a_dst, const int* __restrict__ off,
                                              const int* __restrict__ srcs, const float* __restrict__ ab,
                                              float* __restrict__ H, int N, int do_relu) {
    const int slice = blockIdx.x & 7;
    const int node = (blockIdx.x >> 3) * 4 + (threadIdx.x >> 6);
    if (node >= N) return;
    const int lane = threadIdx.x & 63;
    const int eg = lane >> 4;   // edge group 0..3
    const int cl = lane & 15;   // column within slice
    const int beg = off[node], end = off[node + 1];
    const float adn = a_dst[node] + ab[0];
    const float* Zs = Zb + (size_t)slice * N * 16 + cl;

    float acc = 0.f, ssum = 0.f;
    int i = beg + eg;
    for (; i + 4 < end; i += 8) {
        int s0 = __builtin_nontemporal_load(&srcs[i]);
        int s1 = __builtin_nontemporal_load(&srcs[i + 4]);
        float z0 = Zs[(size_t)s0 * 16];
        float z1 = Zs[(size_t)s1 * 16];
        float e0 = a_src[s0] + adn; e0 = (e0 > 0.f) ? e0 : 0.01f * e0;
        float e1 = a_src[s1] + adn; e1 = (e1 > 0.f) ? e1 : 0.01f * e1;
        float p0 = __expf(e0), p1 = __expf(e1);
        ssum += p0 + p1;
        acc = fmaf(p0, z0, acc);
        acc = fmaf(p1, z1, acc);
    }
    if (i < end) {
        int s0 = __builtin_nontemporal_load(&srcs[i]);
        float z0 = Zs[(size_t)s0 * 16];
        float e0 = a_src[s0] + adn; e0 = (e0 > 0.f) ? e0 : 0.01f * e0;
        float p0 = __expf(e0);
        ssum += p0;
        acc = fmaf(p0, z0, acc);
    }
    // reduce across the 4 edge groups (lane bits 4 and 5)
    ssum += __shfl_xor(ssum, 16); acc += __shfl_xor(acc, 16);
    ssum += __shfl_xor(ssum, 32); acc += __shfl_xor(acc, 32);
    if (eg == 0) {
        float inv = (end > beg) ? 1.0f / ssum : 0.0f;
        float h = acc * inv;
        if (do_relu) h = fmaxf(h, 0.f);
        __builtin_nontemporal_store(h, &H[(size_t)node * DD + slice * 16 + cl]);
    }
}

// ---------------- launcher ----------------

extern "C" void kernel_launch(void* const* d_in, const int* in_sizes, int n_in,
                              void* d_out, int out_size, void* d_ws, size_t ws_size,
                              hipStream_t stream) {
    const float* x  = (const float*)d_in[0];
    const int* src  = (const int*)d_in[1];
    const int* dst  = (const int*)d_in[2];
    const float* Wl[3]  = {(const float*)d_in[4],  (const float*)d_in[8],  (const float*)d_in[12]};
    const float* bl[3]  = {(const float*)d_in[5],  (const float*)d_in[9],  (const float*)d_in[13]};
    const float* aWl[3] = {(const float*)d_in[6],  (const float*)d_in[10], (const float*)d_in[14]};
    const float* abl[3] = {(const float*)d_in[7],  (const float*)d_in[11], (const float*)d_in[15]};
    const int N = in_sizes[0] / DD;
    const int E = in_sizes[1];

    char* p = (char*)d_ws;
    auto alloc = [&](size_t bytes) -> char* {
        char* r = p;
        p += (bytes + 255) & ~(size_t)255;
        return r;
    };
    float* zb   = (float*)alloc((size_t)N * DD * 4);
    float* hA   = (float*)alloc((size_t)N * DD * 4);
    float* hB   = (float*)alloc((size_t)N * DD * 4);
    float* asrc = (float*)alloc((size_t)N * 4);
    float* adst = (float*)alloc((size_t)N * 4);
    int* off    = (int*)alloc((size_t)(N + 1) * 4);
    int* srcs   = (int*)alloc((size_t)E * 4);
    int* gcount = (int*)alloc(512 * 4);
    int* bbase  = (int*)alloc(512 * 4);
    int* bcur   = (int*)alloc(512 * 4);
    // aliases: CSR-build scratch lives in hA/hB, which are only written after off_k
    int2* bufA  = (int2*)hB;      // E * 8 bytes = 12.8 MB <= 25.6 MB
    int* dstS   = (int*)hA;       // E * 4 bytes = 6.4 MB <= 25.6 MB

    const int NBLK1 = (E + P1CHUNK - 1) / P1CHUNK;

    fill_zero_i<<<2, 256, 0, stream>>>(gcount, 512);
    p1hist_k<<<NBLK1, 512, 0, stream>>>(dst, gcount, E);
    p1scan_k<<<1, 512, 0, stream>>>(gcount, bbase, bcur, E);
    p1scatter_k<<<NBLK1, 512, 0, stream>>>(src, dst, bcur, bufA, E);
    p2sort_k<<<NBKT, 512, 0, stream>>>(bufA, bbase, srcs, dstS);
    off_k<<<(E + 511) / 512, 512, 0, stream>>>(dstS, off, N, E);

    const float* in = x;
    float* outs[3] = {hA, hB, (float*)d_out};
    const int aggr_blocks = 8 * ((N + 3) / 4);
    for (int l = 0; l < 3; ++l) {
        gemm_k<<<(N + 63) / 64, 256, 0, stream>>>(in, Wl[l], bl[l], aWl[l], zb, asrc, adst, N);
        aggr_k<<<aggr_blocks, 256, 0, stream>>>(zb, asrc, adst, off, srcs, abl[l], outs[l], N, (l < 2) ? 1 : 0);
        in = outs[l];
    }
}

// Round 9
// 547.005 us; speedup vs baseline: 1.5852x; 1.5852x over previous
//
#include <hip/hip_runtime.h>
#include <math.h>

#define DD 128
#define NBKT 391          // buckets = dst>>7, dst < 50000 -> 0..390
#define P1CHUNK 4096      // edges per block in pass 1
#define P2CAP 8192        // max edges per bucket held in LDS (mean 4096, sigma 64)

// ---------------- generic zero ----------------

__global__ __launch_bounds__(256) void fill_zero_i(int* p, int n) {
    int i = blockIdx.x * 256 + threadIdx.x;
    if (i < n) p[i] = 0;
}

// ---------------- pass 1a: per-bucket global histogram (LDS-staged) ----------------

__global__ __launch_bounds__(512) void p1hist_k(const int* __restrict__ dst, int* __restrict__ gcount, int E) {
    __shared__ int lh[NBKT];
    const int tid = threadIdx.x;
    for (int i = tid; i < NBKT; i += 512) lh[i] = 0;
    __syncthreads();
    const int blk0 = blockIdx.x * P1CHUNK;
    const int blkE = min(blk0 + P1CHUNK, E);
    int i0 = blk0 + tid * 8;
    if (i0 + 8 <= blkE) {
        int4 d0 = *reinterpret_cast<const int4*>(dst + i0);
        int4 d1 = *reinterpret_cast<const int4*>(dst + i0 + 4);
        atomicAdd(&lh[d0.x >> 7], 1); atomicAdd(&lh[d0.y >> 7], 1);
        atomicAdd(&lh[d0.z >> 7], 1); atomicAdd(&lh[d0.w >> 7], 1);
        atomicAdd(&lh[d1.x >> 7], 1); atomicAdd(&lh[d1.y >> 7], 1);
        atomicAdd(&lh[d1.z >> 7], 1); atomicAdd(&lh[d1.w >> 7], 1);
    } else {
        for (int j = 0; j < 8; ++j) {
            int i = i0 + j;
            if (i < blkE) atomicAdd(&lh[dst[i] >> 7], 1);
        }
    }
    __syncthreads();
    for (int i = tid; i < NBKT; i += 512)
        if (lh[i]) atomicAdd(&gcount[i], lh[i]);
}

// ---------------- pass 1b: exclusive scan of 392 bucket counts ----------------

__global__ __launch_bounds__(512) void p1scan_k(const int* __restrict__ gcount, int* __restrict__ bbase,
                                                int* __restrict__ bcur, int E) {
    __shared__ int tmp[512];
    int t = threadIdx.x;
    int v = (t < NBKT) ? gcount[t] : 0;
    tmp[t] = v;
    __syncthreads();
#pragma unroll
    for (int o = 1; o < 512; o <<= 1) {
        int add = (t >= o) ? tmp[t - o] : 0;
        __syncthreads();
        tmp[t] += add;
        __syncthreads();
    }
    if (t <= NBKT) {
        int ex = (t < NBKT) ? (tmp[t] - v) : E;  // t == NBKT -> total = E
        bbase[t] = ex;
        if (t < NBKT) bcur[t] = ex;
    }
}

// ---------------- pass 1c: bucket-binned scatter (LDS-staged, coalesced-run writes) ----------------

__global__ __launch_bounds__(512) void p1scatter_k(const int* __restrict__ src, const int* __restrict__ dst,
                                                   int* __restrict__ bcur, int2* __restrict__ bufA, int E) {
    __shared__ int lcnt[NBKT];     // per-bucket count in this block
    __shared__ int lstart[512];    // exclusive scan (padded)
    __shared__ int blkb[NBKT];     // this block's global base per bucket
    __shared__ int2 stage[P1CHUNK];
    const int tid = threadIdx.x;
    for (int i = tid; i < NBKT; i += 512) lcnt[i] = 0;
    __syncthreads();
    const int blk0 = blockIdx.x * P1CHUNK;
    const int blkE = min(blk0 + P1CHUNK, E);
    const int i0 = blk0 + tid * 8;

    int sv[8], dv[8], bn[8], rk[8], cntT = 0;
    if (i0 + 8 <= blkE) {
        int4 s0 = *reinterpret_cast<const int4*>(src + i0);
        int4 s1 = *reinterpret_cast<const int4*>(src + i0 + 4);
        int4 d0 = *reinterpret_cast<const int4*>(dst + i0);
        int4 d1 = *reinterpret_cast<const int4*>(dst + i0 + 4);
        sv[0] = s0.x; sv[1] = s0.y; sv[2] = s0.z; sv[3] = s0.w;
        sv[4] = s1.x; sv[5] = s1.y; sv[6] = s1.z; sv[7] = s1.w;
        dv[0] = d0.x; dv[1] = d0.y; dv[2] = d0.z; dv[3] = d0.w;
        dv[4] = d1.x; dv[5] = d1.y; dv[6] = d1.z; dv[7] = d1.w;
        cntT = 8;
    } else {
#pragma unroll
        for (int j = 0; j < 8; ++j) {
            int i = i0 + j;
            if (i < blkE) { sv[j] = src[i]; dv[j] = dst[i]; cntT = j + 1; }
        }
    }
#pragma unroll
    for (int j = 0; j < 8; ++j) {
        if (j < cntT) {
            bn[j] = dv[j] >> 7;
            rk[j] = atomicAdd(&lcnt[bn[j]], 1);
        }
    }
    __syncthreads();
    // exclusive scan lcnt -> lstart (Hillis-Steele over padded 512)
    int v = (tid < NBKT) ? lcnt[tid] : 0;
    lstart[tid] = v;
    __syncthreads();
#pragma unroll
    for (int o = 1; o < 512; o <<= 1) {
        int add = (tid >= o) ? lstart[tid - o] : 0;
        __syncthreads();
        lstart[tid] += add;
        __syncthreads();
    }
    lstart[tid] -= v;  // exclusive
    __syncthreads();
    // reserve global ranges
    for (int i = tid; i < NBKT; i += 512)
        blkb[i] = lcnt[i] ? atomicAdd(&bcur[i], lcnt[i]) : 0;
    // stage into LDS ordered by bucket
#pragma unroll
    for (int j = 0; j < 8; ++j) {
        if (j < cntT) {
            int pos = lstart[bn[j]] + rk[j];
            stage[pos] = make_int2(sv[j], dv[j]);
        }
    }
    __syncthreads();
    // linear write-out: consecutive j within a bucket-run -> consecutive global
    const int cnt = blkE - blk0;
    for (int j = tid; j < cnt; j += 512) {
        int2 e = stage[j];
        int b = e.y >> 7;
        bufA[blkb[b] + (j - lstart[b])] = e;
    }
}

// ---------------- pass 2: per-bucket LDS counting sort by dst&127 ----------------

__global__ __launch_bounds__(512) void p2sort_k(const int2* __restrict__ bufA, const int* __restrict__ bbase,
                                                int* __restrict__ srcs, int* __restrict__ dstS) {
    __shared__ int h2[128];
    __shared__ int start2[128];
    __shared__ int cur2[128];
    __shared__ int ssrc[P2CAP];
    __shared__ int sdst[P2CAP];
    const int tid = threadIdx.x;
    const int b = blockIdx.x;
    const int base = bbase[b];
    const int cnt = bbase[b + 1] - base;
    for (int i = tid; i < 128; i += 512) h2[i] = 0;
    __syncthreads();
    for (int j = tid; j < cnt; j += 512)
        atomicAdd(&h2[bufA[base + j].y & 127], 1);
    __syncthreads();
    if (tid == 0) {
        int s = 0;
        for (int i = 0; i < 128; ++i) { start2[i] = s; cur2[i] = s; s += h2[i]; }
    }
    __syncthreads();
    for (int j = tid; j < cnt; j += 512) {
        int2 e = bufA[base + j];
        int p = atomicAdd(&cur2[e.y & 127], 1);
        ssrc[p] = e.x;
        sdst[p] = e.y;
    }
    __syncthreads();
    for (int j = tid; j < cnt; j += 512) {
        srcs[base + j] = ssrc[j];
        dstS[base + j] = sdst[j];
    }
}

// ---------------- CSR offsets from sorted dst (boundary detection) ----------------

__global__ __launch_bounds__(512) void off_k(const int* __restrict__ dstS, int* __restrict__ off, int N, int E) {
    int i = blockIdx.x * 512 + threadIdx.x;
    if (i >= E) return;
    int d = dstS[i];
    int p = (i == 0) ? -1 : dstS[i - 1];
    if (d != p)
        for (int n = p + 1; n <= d; ++n) off[n] = i;
    if (i == E - 1)
        for (int n = d + 1; n <= N; ++n) off[n] = E;
}

// ---------------- GEMM: Zb = blocked(X @ W^T + b), fused attn halves ----------------
// Zb layout: Zb[c][node][16] for c = 0..7 (columns 16c..16c+15) -> per-slice
// footprint 3.2 MB, L2-resident on one XCD during aggregation.

__global__ __launch_bounds__(256) void gemm_k(const float* __restrict__ X, const float* __restrict__ W,
                                              const float* __restrict__ B, const float* __restrict__ aW,
                                              float* __restrict__ Zb, float* __restrict__ a_src,
                                              float* __restrict__ a_dst, int N) {
    __shared__ __align__(16) float xs[32][64];   // transposed x chunk: xs[k][r]
    __shared__ __align__(16) float ws[32][128];  // transposed w chunk: ws[k][o]
    const int tid = threadIdx.x;
    const int row0 = blockIdx.x * 64;
    const int cg = tid & 31;  // 32 col groups of 4 cols
    const int rg = tid >> 5;  // 8 row groups of 8 rows
    float acc[8][4];
#pragma unroll
    for (int i = 0; i < 8; ++i)
#pragma unroll
        for (int j = 0; j < 4; ++j) acc[i][j] = 0.f;

    for (int kc = 0; kc < DD; kc += 32) {
        {
            int r = tid >> 2;
            int k4 = (tid & 3) * 8;
            int gr = row0 + r;
            if (gr >= N) gr = N - 1;
            const float4* p = reinterpret_cast<const float4*>(X + (size_t)gr * DD + kc + k4);
            float4 v0 = p[0], v1 = p[1];
            xs[k4 + 0][r] = v0.x; xs[k4 + 1][r] = v0.y; xs[k4 + 2][r] = v0.z; xs[k4 + 3][r] = v0.w;
            xs[k4 + 4][r] = v1.x; xs[k4 + 5][r] = v1.y; xs[k4 + 6][r] = v1.z; xs[k4 + 7][r] = v1.w;
        }
        {
            int o = tid >> 1;
            int k8 = (tid & 1) * 16;
            const float4* p = reinterpret_cast<const float4*>(W + (size_t)o * DD + kc + k8);
            float4 v0 = p[0], v1 = p[1], v2 = p[2], v3 = p[3];
            ws[k8 + 0][o] = v0.x;  ws[k8 + 1][o] = v0.y;  ws[k8 + 2][o] = v0.z;  ws[k8 + 3][o] = v0.w;
            ws[k8 + 4][o] = v1.x;  ws[k8 + 5][o] = v1.y;  ws[k8 + 6][o] = v1.z;  ws[k8 + 7][o] = v1.w;
            ws[k8 + 8][o] = v2.x;  ws[k8 + 9][o] = v2.y;  ws[k8 + 10][o] = v2.z; ws[k8 + 11][o] = v2.w;
            ws[k8 + 12][o] = v3.x; ws[k8 + 13][o] = v3.y; ws[k8 + 14][o] = v3.z; ws[k8 + 15][o] = v3.w;
        }
        __syncthreads();
#pragma unroll
        for (int k = 0; k < 32; ++k) {
            const float4 wv = *reinterpret_cast<const float4*>(&ws[k][cg * 4]);
            const float4 xa = *reinterpret_cast<const float4*>(&xs[k][rg * 8]);
            const float4 xb = *reinterpret_cast<const float4*>(&xs[k][rg * 8 + 4]);
            float xr[8] = {xa.x, xa.y, xa.z, xa.w, xb.x, xb.y, xb.z, xb.w};
            float wr[4] = {wv.x, wv.y, wv.z, wv.w};
#pragma unroll
            for (int i = 0; i < 8; ++i)
#pragma unroll
                for (int j = 0; j < 4; ++j)
                    acc[i][j] = fmaf(xr[i], wr[j], acc[i][j]);
        }
        __syncthreads();
    }
    const int c0 = cg * 4;
    const float4 bv = *reinterpret_cast<const float4*>(B + c0);
    const float4 aw0 = *reinterpret_cast<const float4*>(aW + c0);
    const float4 aw1 = *reinterpret_cast<const float4*>(aW + DD + c0);
    float pa[8], pb[8];
#pragma unroll
    for (int i = 0; i < 8; ++i) {
        acc[i][0] += bv.x; acc[i][1] += bv.y; acc[i][2] += bv.z; acc[i][3] += bv.w;
        pa[i] = acc[i][0] * aw0.x + acc[i][1] * aw0.y + acc[i][2] * aw0.z + acc[i][3] * aw0.w;
        pb[i] = acc[i][0] * aw1.x + acc[i][1] * aw1.y + acc[i][2] * aw1.z + acc[i][3] * aw1.w;
    }
#pragma unroll
    for (int o = 1; o < 32; o <<= 1) {
#pragma unroll
        for (int i = 0; i < 8; ++i) {
            pa[i] += __shfl_xor(pa[i], o);
            pb[i] += __shfl_xor(pb[i], o);
        }
    }
    const int cblk = c0 >> 4;   // feature slice 0..7
    const int cin = c0 & 15;    // column within slice
#pragma unroll
    for (int i = 0; i < 8; ++i) {
        int gr = row0 + rg * 8 + i;
        if (gr < N) {
            *reinterpret_cast<float4*>(Zb + ((size_t)cblk * N + gr) * 16 + cin) =
                *reinterpret_cast<const float4*>(&acc[i][0]);
            if (cg == 0) {
                a_src[gr] = pa[i];
                a_dst[gr] = pb[i];
            }
        }
    }
}

// ---------------- per-edge unnormalized softmax weight, computed ONCE per layer ----------------
// pair[i] = (src, p = exp(leaky(a_src[src] + a_dst[node] + ab)))

__global__ __launch_bounds__(256) void alpha_k(const float* __restrict__ a_src, const float* __restrict__ a_dst,
                                               const int* __restrict__ off, const int* __restrict__ srcs,
                                               const float* __restrict__ ab, int2* __restrict__ pair, int N) {
    int node = blockIdx.x * 4 + (threadIdx.x >> 6);
    int lane = threadIdx.x & 63;
    if (node >= N) return;
    const int beg = off[node], end = off[node + 1];
    const float adn = a_dst[node] + ab[0];
    for (int i = beg + lane; i < end; i += 64) {
        int s = srcs[i];
        float e = a_src[s] + adn;
        e = (e > 0.f) ? e : 0.01f * e;
        float p = __expf(e);
        pair[i] = make_int2(s, __float_as_int(p));
    }
}

// ---------------- sliced weighted SpMM: H[:,16c:16c+16] = norm(A) @ Zb[c] ----------------
// XCD feature-sharding (slice = blockIdx&7 -> XCD round-robin; 3.2MB slice L2-resident).
// Wave = 16 edges x 4 lanes (one float4 each); psum accumulated alongside so no
// pre-normalization needed. Unroll x2 (avg degree 32 -> 1 iteration).

__global__ __launch_bounds__(256) void aggr_k(const float* __restrict__ Zb, const int2* __restrict__ pair,
                                              const int* __restrict__ off, float* __restrict__ H,
                                              int N, int do_relu) {
    const int slice = blockIdx.x & 7;
    const int node = (blockIdx.x >> 3) * 4 + (threadIdx.x >> 6);
    if (node >= N) return;
    const int lane = threadIdx.x & 63;
    const int eg = lane >> 2;   // edge 0..15 within the group
    const int ql = lane & 3;    // float4 position within the 16-float slice
    const int beg = off[node], end = off[node + 1];
    const int cnt = end - beg;
    const float* Zs = Zb + (size_t)slice * N * 16 + ql * 4;

    float4 acc = {0.f, 0.f, 0.f, 0.f};
    float psum = 0.f;
    for (int it = 0; it < cnt; it += 32) {
        int i0 = beg + it + eg;
        int i1 = i0 + 16;
        bool v0 = (i0 < end), v1 = (i1 < end);
        int2 pr0 = pair[v0 ? i0 : beg];
        int2 pr1 = pair[v1 ? i1 : beg];
        float a0 = v0 ? __int_as_float(pr0.y) : 0.f;
        float a1 = v1 ? __int_as_float(pr1.y) : 0.f;
        const float4 z0 = *reinterpret_cast<const float4*>(Zs + (size_t)pr0.x * 16);
        const float4 z1 = *reinterpret_cast<const float4*>(Zs + (size_t)pr1.x * 16);
        acc.x = fmaf(a0, z0.x, acc.x); acc.y = fmaf(a0, z0.y, acc.y);
        acc.z = fmaf(a0, z0.z, acc.z); acc.w = fmaf(a0, z0.w, acc.w);
        acc.x = fmaf(a1, z1.x, acc.x); acc.y = fmaf(a1, z1.y, acc.y);
        acc.z = fmaf(a1, z1.z, acc.z); acc.w = fmaf(a1, z1.w, acc.w);
        psum += a0 + a1;
    }
    // reduce over the 16 edge lanes (lane bits 2..5); ql lanes hold duplicates of psum
#pragma unroll
    for (int o = 4; o < 64; o <<= 1) {
        acc.x += __shfl_xor(acc.x, o);
        acc.y += __shfl_xor(acc.y, o);
        acc.z += __shfl_xor(acc.z, o);
        acc.w += __shfl_xor(acc.w, o);
        psum  += __shfl_xor(psum, o);
    }
    if (eg == 0) {
        float inv = (cnt > 0) ? 1.0f / psum : 0.0f;
        float hx = acc.x * inv, hy = acc.y * inv, hz = acc.z * inv, hw = acc.w * inv;
        if (do_relu) {
            hx = fmaxf(hx, 0.f); hy = fmaxf(hy, 0.f);
            hz = fmaxf(hz, 0.f); hw = fmaxf(hw, 0.f);
        }
        float* out = H + (size_t)node * DD + slice * 16 + ql * 4;
        __builtin_nontemporal_store(hx, out + 0);
        __builtin_nontemporal_store(hy, out + 1);
        __builtin_nontemporal_store(hz, out + 2);
        __builtin_nontemporal_store(hw, out + 3);
    }
}

// ---------------- launcher ----------------

extern "C" void kernel_launch(void* const* d_in, const int* in_sizes, int n_in,
                              void* d_out, int out_size, void* d_ws, size_t ws_size,
                              hipStream_t stream) {
    const float* x  = (const float*)d_in[0];
    const int* src  = (const int*)d_in[1];
    const int* dst  = (const int*)d_in[2];
    const float* Wl[3]  = {(const float*)d_in[4],  (const float*)d_in[8],  (const float*)d_in[12]};
    const float* bl[3]  = {(const float*)d_in[5],  (const float*)d_in[9],  (const float*)d_in[13]};
    const float* aWl[3] = {(const float*)d_in[6],  (const float*)d_in[10], (const float*)d_in[14]};
    const float* abl[3] = {(const float*)d_in[7],  (const float*)d_in[11], (const float*)d_in[15]};
    const int N = in_sizes[0] / DD;
    const int E = in_sizes[1];

    char* p = (char*)d_ws;
    auto alloc = [&](size_t bytes) -> char* {
        char* r = p;
        p += (bytes + 255) & ~(size_t)255;
        return r;
    };
    float* zb   = (float*)alloc((size_t)N * DD * 4);
    float* hA   = (float*)alloc((size_t)N * DD * 4);
    float* hB   = (float*)alloc((size_t)N * DD * 4);
    float* asrc = (float*)alloc((size_t)N * 4);
    float* adst = (float*)alloc((size_t)N * 4);
    int* off    = (int*)alloc((size_t)(N + 1) * 4);
    int* srcs   = (int*)alloc((size_t)E * 4);
    int2* pair  = (int2*)alloc((size_t)E * 8);
    int* gcount = (int*)alloc(512 * 4);
    int* bbase  = (int*)alloc(512 * 4);
    int* bcur   = (int*)alloc(512 * 4);
    // aliases: CSR-build scratch lives in hA/hB, which are only written after off_k
    int2* bufA  = (int2*)hB;      // E * 8 bytes = 12.8 MB <= 25.6 MB
    int* dstS   = (int*)hA;       // E * 4 bytes = 6.4 MB <= 25.6 MB

    const int NBLK1 = (E + P1CHUNK - 1) / P1CHUNK;

    fill_zero_i<<<2, 256, 0, stream>>>(gcount, 512);
    p1hist_k<<<NBLK1, 512, 0, stream>>>(dst, gcount, E);
    p1scan_k<<<1, 512, 0, stream>>>(gcount, bbase, bcur, E);
    p1scatter_k<<<NBLK1, 512, 0, stream>>>(src, dst, bcur, bufA, E);
    p2sort_k<<<NBKT, 512, 0, stream>>>(bufA, bbase, srcs, dstS);
    off_k<<<(E + 511) / 512, 512, 0, stream>>>(dstS, off, N, E);

    const float* in = x;
    float* outs[3] = {hA, hB, (float*)d_out};
    const int node_blocks = (N + 3) / 4;
    for (int l = 0; l < 3; ++l) {
        gemm_k<<<(N + 63) / 64, 256, 0, stream>>>(in, Wl[l], bl[l], aWl[l], zb, asrc, adst, N);
        alpha_k<<<node_blocks, 256, 0, stream>>>(asrc, adst, off, srcs, abl[l], pair, N);
        aggr_k<<<8 * node_blocks, 256, 0, stream>>>(zb, pair, off, outs[l], N, (l < 2) ? 1 : 0);
        in = outs[l];
    }
}

// Round 10
// 445.318 us; speedup vs baseline: 1.9472x; 1.2283x over previous
//
#include <hip/hip_runtime.h>
#include <math.h>

#define DD 128
#define NBKT 391          // buckets = dst>>7, dst < 50000 -> 0..390
#define P1CHUNK 4096      // edges per block in pass 1
#define P2CAP 8192        // max edges per bucket held in LDS (mean 4096, sigma 64)

// ---------------- generic zero ----------------

__global__ __launch_bounds__(256) void fill_zero_i(int* p, int n) {
    int i = blockIdx.x * 256 + threadIdx.x;
    if (i < n) p[i] = 0;
}

// ---------------- pass 1a: per-bucket global histogram (LDS-staged) ----------------

__global__ __launch_bounds__(512) void p1hist_k(const int* __restrict__ dst, int* __restrict__ gcount, int E) {
    __shared__ int lh[NBKT];
    const int tid = threadIdx.x;
    for (int i = tid; i < NBKT; i += 512) lh[i] = 0;
    __syncthreads();
    const int blk0 = blockIdx.x * P1CHUNK;
    const int blkE = min(blk0 + P1CHUNK, E);
    int i0 = blk0 + tid * 8;
    if (i0 + 8 <= blkE) {
        int4 d0 = *reinterpret_cast<const int4*>(dst + i0);
        int4 d1 = *reinterpret_cast<const int4*>(dst + i0 + 4);
        atomicAdd(&lh[d0.x >> 7], 1); atomicAdd(&lh[d0.y >> 7], 1);
        atomicAdd(&lh[d0.z >> 7], 1); atomicAdd(&lh[d0.w >> 7], 1);
        atomicAdd(&lh[d1.x >> 7], 1); atomicAdd(&lh[d1.y >> 7], 1);
        atomicAdd(&lh[d1.z >> 7], 1); atomicAdd(&lh[d1.w >> 7], 1);
    } else {
        for (int j = 0; j < 8; ++j) {
            int i = i0 + j;
            if (i < blkE) atomicAdd(&lh[dst[i] >> 7], 1);
        }
    }
    __syncthreads();
    for (int i = tid; i < NBKT; i += 512)
        if (lh[i]) atomicAdd(&gcount[i], lh[i]);
}

// ---------------- pass 1b: exclusive scan of 392 bucket counts ----------------

__global__ __launch_bounds__(512) void p1scan_k(const int* __restrict__ gcount, int* __restrict__ bbase,
                                                int* __restrict__ bcur, int E) {
    __shared__ int tmp[512];
    int t = threadIdx.x;
    int v = (t < NBKT) ? gcount[t] : 0;
    tmp[t] = v;
    __syncthreads();
#pragma unroll
    for (int o = 1; o < 512; o <<= 1) {
        int add = (t >= o) ? tmp[t - o] : 0;
        __syncthreads();
        tmp[t] += add;
        __syncthreads();
    }
    if (t <= NBKT) {
        int ex = (t < NBKT) ? (tmp[t] - v) : E;  // t == NBKT -> total = E
        bbase[t] = ex;
        if (t < NBKT) bcur[t] = ex;
    }
}

// ---------------- pass 1c: bucket-binned scatter (LDS-staged, coalesced-run writes) ----------------

__global__ __launch_bounds__(512) void p1scatter_k(const int* __restrict__ src, const int* __restrict__ dst,
                                                   int* __restrict__ bcur, int2* __restrict__ bufA, int E) {
    __shared__ int lcnt[NBKT];     // per-bucket count in this block
    __shared__ int lstart[512];    // exclusive scan (padded)
    __shared__ int blkb[NBKT];     // this block's global base per bucket
    __shared__ int2 stage[P1CHUNK];
    const int tid = threadIdx.x;
    for (int i = tid; i < NBKT; i += 512) lcnt[i] = 0;
    __syncthreads();
    const int blk0 = blockIdx.x * P1CHUNK;
    const int blkE = min(blk0 + P1CHUNK, E);
    const int i0 = blk0 + tid * 8;

    int sv[8], dv[8], bn[8], rk[8], cntT = 0;
    if (i0 + 8 <= blkE) {
        int4 s0 = *reinterpret_cast<const int4*>(src + i0);
        int4 s1 = *reinterpret_cast<const int4*>(src + i0 + 4);
        int4 d0 = *reinterpret_cast<const int4*>(dst + i0);
        int4 d1 = *reinterpret_cast<const int4*>(dst + i0 + 4);
        sv[0] = s0.x; sv[1] = s0.y; sv[2] = s0.z; sv[3] = s0.w;
        sv[4] = s1.x; sv[5] = s1.y; sv[6] = s1.z; sv[7] = s1.w;
        dv[0] = d0.x; dv[1] = d0.y; dv[2] = d0.z; dv[3] = d0.w;
        dv[4] = d1.x; dv[5] = d1.y; dv[6] = d1.z; dv[7] = d1.w;
        cntT = 8;
    } else {
#pragma unroll
        for (int j = 0; j < 8; ++j) {
            int i = i0 + j;
            if (i < blkE) { sv[j] = src[i]; dv[j] = dst[i]; cntT = j + 1; }
        }
    }
#pragma unroll
    for (int j = 0; j < 8; ++j) {
        if (j < cntT) {
            bn[j] = dv[j] >> 7;
            rk[j] = atomicAdd(&lcnt[bn[j]], 1);
        }
    }
    __syncthreads();
    // exclusive scan lcnt -> lstart (Hillis-Steele over padded 512)
    int v = (tid < NBKT) ? lcnt[tid] : 0;
    lstart[tid] = v;
    __syncthreads();
#pragma unroll
    for (int o = 1; o < 512; o <<= 1) {
        int add = (tid >= o) ? lstart[tid - o] : 0;
        __syncthreads();
        lstart[tid] += add;
        __syncthreads();
    }
    lstart[tid] -= v;  // exclusive
    __syncthreads();
    // reserve global ranges
    for (int i = tid; i < NBKT; i += 512)
        blkb[i] = lcnt[i] ? atomicAdd(&bcur[i], lcnt[i]) : 0;
    // stage into LDS ordered by bucket
#pragma unroll
    for (int j = 0; j < 8; ++j) {
        if (j < cntT) {
            int pos = lstart[bn[j]] + rk[j];
            stage[pos] = make_int2(sv[j], dv[j]);
        }
    }
    __syncthreads();
    // linear write-out: consecutive j within a bucket-run -> consecutive global
    const int cnt = blkE - blk0;
    for (int j = tid; j < cnt; j += 512) {
        int2 e = stage[j];
        int b = e.y >> 7;
        bufA[blkb[b] + (j - lstart[b])] = e;
    }
}

// ---------------- pass 2: per-bucket LDS counting sort by dst&127 ----------------

__global__ __launch_bounds__(512) void p2sort_k(const int2* __restrict__ bufA, const int* __restrict__ bbase,
                                                int* __restrict__ srcs, int* __restrict__ dstS) {
    __shared__ int h2[128];
    __shared__ int start2[128];
    __shared__ int cur2[128];
    __shared__ int ssrc[P2CAP];
    __shared__ int sdst[P2CAP];
    const int tid = threadIdx.x;
    const int b = blockIdx.x;
    const int base = bbase[b];
    const int cnt = bbase[b + 1] - base;
    for (int i = tid; i < 128; i += 512) h2[i] = 0;
    __syncthreads();
    for (int j = tid; j < cnt; j += 512)
        atomicAdd(&h2[bufA[base + j].y & 127], 1);
    __syncthreads();
    if (tid == 0) {
        int s = 0;
        for (int i = 0; i < 128; ++i) { start2[i] = s; cur2[i] = s; s += h2[i]; }
    }
    __syncthreads();
    for (int j = tid; j < cnt; j += 512) {
        int2 e = bufA[base + j];
        int p = atomicAdd(&cur2[e.y & 127], 1);
        ssrc[p] = e.x;
        sdst[p] = e.y;
    }
    __syncthreads();
    for (int j = tid; j < cnt; j += 512) {
        srcs[base + j] = ssrc[j];
        dstS[base + j] = sdst[j];
    }
}

// ---------------- CSR offsets from sorted dst (boundary detection) ----------------

__global__ __launch_bounds__(512) void off_k(const int* __restrict__ dstS, int* __restrict__ off, int N, int E) {
    int i = blockIdx.x * 512 + threadIdx.x;
    if (i >= E) return;
    int d = dstS[i];
    int p = (i == 0) ? -1 : dstS[i - 1];
    if (d != p)
        for (int n = p + 1; n <= d; ++n) off[n] = i;
    if (i == E - 1)
        for (int n = d + 1; n <= N; ++n) off[n] = E;
}

// ---------------- GEMM: Zb = blocked(X @ W^T + b), fused attn halves ----------------
// Zb layout: Zb[c][node][16] for c = 0..7 (columns 16c..16c+15) -> per-slice
// footprint 3.2 MB, L2-resident on one XCD during aggregation.

__global__ __launch_bounds__(256) void gemm_k(const float* __restrict__ X, const float* __restrict__ W,
                                              const float* __restrict__ B, const float* __restrict__ aW,
                                              float* __restrict__ Zb, float* __restrict__ a_src,
                                              float* __restrict__ a_dst, int N) {
    __shared__ __align__(16) float xs[32][64];   // transposed x chunk: xs[k][r]
    __shared__ __align__(16) float ws[32][128];  // transposed w chunk: ws[k][o]
    const int tid = threadIdx.x;
    const int row0 = blockIdx.x * 64;
    const int cg = tid & 31;  // 32 col groups of 4 cols
    const int rg = tid >> 5;  // 8 row groups of 8 rows
    float acc[8][4];
#pragma unroll
    for (int i = 0; i < 8; ++i)
#pragma unroll
        for (int j = 0; j < 4; ++j) acc[i][j] = 0.f;

    for (int kc = 0; kc < DD; kc += 32) {
        {
            int r = tid >> 2;
            int k4 = (tid & 3) * 8;
            int gr = row0 + r;
            if (gr >= N) gr = N - 1;
            const float4* p = reinterpret_cast<const float4*>(X + (size_t)gr * DD + kc + k4);
            float4 v0 = p[0], v1 = p[1];
            xs[k4 + 0][r] = v0.x; xs[k4 + 1][r] = v0.y; xs[k4 + 2][r] = v0.z; xs[k4 + 3][r] = v0.w;
            xs[k4 + 4][r] = v1.x; xs[k4 + 5][r] = v1.y; xs[k4 + 6][r] = v1.z; xs[k4 + 7][r] = v1.w;
        }
        {
            int o = tid >> 1;
            int k8 = (tid & 1) * 16;
            const float4* p = reinterpret_cast<const float4*>(W + (size_t)o * DD + kc + k8);
            float4 v0 = p[0], v1 = p[1], v2 = p[2], v3 = p[3];
            ws[k8 + 0][o] = v0.x;  ws[k8 + 1][o] = v0.y;  ws[k8 + 2][o] = v0.z;  ws[k8 + 3][o] = v0.w;
            ws[k8 + 4][o] = v1.x;  ws[k8 + 5][o] = v1.y;  ws[k8 + 6][o] = v1.z;  ws[k8 + 7][o] = v1.w;
            ws[k8 + 8][o] = v2.x;  ws[k8 + 9][o] = v2.y;  ws[k8 + 10][o] = v2.z; ws[k8 + 11][o] = v2.w;
            ws[k8 + 12][o] = v3.x; ws[k8 + 13][o] = v3.y; ws[k8 + 14][o] = v3.z; ws[k8 + 15][o] = v3.w;
        }
        __syncthreads();
#pragma unroll
        for (int k = 0; k < 32; ++k) {
            const float4 wv = *reinterpret_cast<const float4*>(&ws[k][cg * 4]);
            const float4 xa = *reinterpret_cast<const float4*>(&xs[k][rg * 8]);
            const float4 xb = *reinterpret_cast<const float4*>(&xs[k][rg * 8 + 4]);
            float xr[8] = {xa.x, xa.y, xa.z, xa.w, xb.x, xb.y, xb.z, xb.w};
            float wr[4] = {wv.x, wv.y, wv.z, wv.w};
#pragma unroll
            for (int i = 0; i < 8; ++i)
#pragma unroll
                for (int j = 0; j < 4; ++j)
                    acc[i][j] = fmaf(xr[i], wr[j], acc[i][j]);
        }
        __syncthreads();
    }
    const int c0 = cg * 4;
    const float4 bv = *reinterpret_cast<const float4*>(B + c0);
    const float4 aw0 = *reinterpret_cast<const float4*>(aW + c0);
    const float4 aw1 = *reinterpret_cast<const float4*>(aW + DD + c0);
    float pa[8], pb[8];
#pragma unroll
    for (int i = 0; i < 8; ++i) {
        acc[i][0] += bv.x; acc[i][1] += bv.y; acc[i][2] += bv.z; acc[i][3] += bv.w;
        pa[i] = acc[i][0] * aw0.x + acc[i][1] * aw0.y + acc[i][2] * aw0.z + acc[i][3] * aw0.w;
        pb[i] = acc[i][0] * aw1.x + acc[i][1] * aw1.y + acc[i][2] * aw1.z + acc[i][3] * aw1.w;
    }
#pragma unroll
    for (int o = 1; o < 32; o <<= 1) {
#pragma unroll
        for (int i = 0; i < 8; ++i) {
            pa[i] += __shfl_xor(pa[i], o);
            pb[i] += __shfl_xor(pb[i], o);
        }
    }
    const int cblk = c0 >> 4;   // feature slice 0..7
    const int cin = c0 & 15;    // column within slice
#pragma unroll
    for (int i = 0; i < 8; ++i) {
        int gr = row0 + rg * 8 + i;
        if (gr < N) {
            *reinterpret_cast<float4*>(Zb + ((size_t)cblk * N + gr) * 16 + cin) =
                *reinterpret_cast<const float4*>(&acc[i][0]);
            if (cg == 0) {
                a_src[gr] = pa[i];
                a_dst[gr] = pb[i];
            }
        }
    }
}

// ---------------- per-edge NORMALIZED softmax weight, computed ONCE per layer ----------------
// pair[i] = (src, alpha = exp(leaky(e)) / sum_over_segment) -- aggr needs no psum/divide.

__global__ __launch_bounds__(256) void alpha_k(const float* __restrict__ a_src, const float* __restrict__ a_dst,
                                               const int* __restrict__ off, const int* __restrict__ srcs,
                                               const float* __restrict__ ab, int2* __restrict__ pair, int N) {
    int node = blockIdx.x * 4 + (threadIdx.x >> 6);
    int lane = threadIdx.x & 63;
    if (node >= N) return;
    const int beg = off[node], end = off[node + 1];
    const float adn = a_dst[node] + ab[0];
    const int i0 = beg + lane;
    float psum = 0.f;
    int s0 = 0; float p0 = 0.f;
    for (int i = i0; i < end; i += 64) {
        int s = srcs[i];
        float e = a_src[s] + adn;
        e = (e > 0.f) ? e : 0.01f * e;
        float p = __expf(e);
        if (i == i0) { s0 = s; p0 = p; }
        else pair[i] = make_int2(s, __float_as_int(p));  // rare (deg > 64): normalized below
        psum += p;
    }
#pragma unroll
    for (int o = 1; o < 64; o <<= 1) psum += __shfl_xor(psum, o);
    const float inv = (end > beg) ? 1.0f / psum : 0.0f;
    if (i0 < end) pair[i0] = make_int2(s0, __float_as_int(p0 * inv));
    for (int i = i0 + 64; i < end; i += 64) {
        int2 pr = pair[i];
        pair[i] = make_int2(pr.x, __float_as_int(__int_as_float(pr.y) * inv));
    }
}

// ---------------- sliced weighted SpMM: H[:,16c:16c+16] = A_norm @ Zb[c] ----------------
// XCD feature-sharding (slice = blockIdx&7). Wave = 4 nodes x 4 edge-slots x 4
// col-float4s -> fixed overhead amortized over 4 node-slices, reduce = 2 shuffle
// levels, pure fma loop (alpha pre-normalized). Unroll x2.

__global__ __launch_bounds__(256) void aggr_k(const float* __restrict__ Zb, const int2* __restrict__ pair,
                                              const int* __restrict__ off, float* __restrict__ H,
                                              int N, int do_relu) {
    const int slice = blockIdx.x & 7;
    const int lane = threadIdx.x & 63;
    const int wid = threadIdx.x >> 6;        // wave 0..3 in block
    const int ng = lane >> 4;                // node group 0..3 in wave
    const int node = (blockIdx.x >> 3) * 16 + wid * 4 + ng;
    if (node >= N) return;
    const int eg = (lane >> 2) & 3;          // edge slot 0..3
    const int ql = lane & 3;                 // float4 position in 16-col slice
    const int beg = off[node], end = off[node + 1];
    const float* Zs = Zb + (size_t)slice * N * 16 + ql * 4;

    float4 acc = {0.f, 0.f, 0.f, 0.f};
    for (int i = beg + eg; i < end; i += 8) {
        int i1 = i + 4;
        bool v1 = (i1 < end);
        int2 pr0 = pair[i];
        int2 pr1 = pair[v1 ? i1 : i];
        float a0 = __int_as_float(pr0.y);
        float a1 = v1 ? __int_as_float(pr1.y) : 0.f;
        const float4 z0 = *reinterpret_cast<const float4*>(Zs + (size_t)pr0.x * 16);
        const float4 z1 = *reinterpret_cast<const float4*>(Zs + (size_t)pr1.x * 16);
        acc.x = fmaf(a0, z0.x, acc.x); acc.y = fmaf(a0, z0.y, acc.y);
        acc.z = fmaf(a0, z0.z, acc.z); acc.w = fmaf(a0, z0.w, acc.w);
        acc.x = fmaf(a1, z1.x, acc.x); acc.y = fmaf(a1, z1.y, acc.y);
        acc.z = fmaf(a1, z1.z, acc.z); acc.w = fmaf(a1, z1.w, acc.w);
    }
    // combine the 4 edge slots (lane bits 2,3)
    acc.x += __shfl_xor(acc.x, 4); acc.y += __shfl_xor(acc.y, 4);
    acc.z += __shfl_xor(acc.z, 4); acc.w += __shfl_xor(acc.w, 4);
    acc.x += __shfl_xor(acc.x, 8); acc.y += __shfl_xor(acc.y, 8);
    acc.z += __shfl_xor(acc.z, 8); acc.w += __shfl_xor(acc.w, 8);
    if (eg == 0) {
        float hx = acc.x, hy = acc.y, hz = acc.z, hw = acc.w;
        if (do_relu) {
            hx = fmaxf(hx, 0.f); hy = fmaxf(hy, 0.f);
            hz = fmaxf(hz, 0.f); hw = fmaxf(hw, 0.f);
        }
        float* out = H + (size_t)node * DD + slice * 16 + ql * 4;
        __builtin_nontemporal_store(hx, out + 0);
        __builtin_nontemporal_store(hy, out + 1);
        __builtin_nontemporal_store(hz, out + 2);
        __builtin_nontemporal_store(hw, out + 3);
    }
}

// ---------------- launcher ----------------

extern "C" void kernel_launch(void* const* d_in, const int* in_sizes, int n_in,
                              void* d_out, int out_size, void* d_ws, size_t ws_size,
                              hipStream_t stream) {
    const float* x  = (const float*)d_in[0];
    const int* src  = (const int*)d_in[1];
    const int* dst  = (const int*)d_in[2];
    const float* Wl[3]  = {(const float*)d_in[4],  (const float*)d_in[8],  (const float*)d_in[12]};
    const float* bl[3]  = {(const float*)d_in[5],  (const float*)d_in[9],  (const float*)d_in[13]};
    const float* aWl[3] = {(const float*)d_in[6],  (const float*)d_in[10], (const float*)d_in[14]};
    const float* abl[3] = {(const float*)d_in[7],  (const float*)d_in[11], (const float*)d_in[15]};
    const int N = in_sizes[0] / DD;
    const int E = in_sizes[1];

    char* p = (char*)d_ws;
    auto alloc = [&](size_t bytes) -> char* {
        char* r = p;
        p += (bytes + 255) & ~(size_t)255;
        return r;
    };
    float* zb   = (float*)alloc((size_t)N * DD * 4);
    float* hA   = (float*)alloc((size_t)N * DD * 4);
    float* hB   = (float*)alloc((size_t)N * DD * 4);
    float* asrc = (float*)alloc((size_t)N * 4);
    float* adst = (float*)alloc((size_t)N * 4);
    int* off    = (int*)alloc((size_t)(N + 1) * 4);
    int* srcs   = (int*)alloc((size_t)E * 4);
    int2* pair  = (int2*)alloc((size_t)E * 8);
    int* gcount = (int*)alloc(512 * 4);
    int* bbase  = (int*)alloc(512 * 4);
    int* bcur   = (int*)alloc(512 * 4);
    // aliases: CSR-build scratch lives in hA/hB, which are only written after off_k
    int2* bufA  = (int2*)hB;      // E * 8 bytes = 12.8 MB <= 25.6 MB
    int* dstS   = (int*)hA;       // E * 4 bytes = 6.4 MB <= 25.6 MB

    const int NBLK1 = (E + P1CHUNK - 1) / P1CHUNK;

    fill_zero_i<<<2, 256, 0, stream>>>(gcount, 512);
    p1hist_k<<<NBLK1, 512, 0, stream>>>(dst, gcount, E);
    p1scan_k<<<1, 512, 0, stream>>>(gcount, bbase, bcur, E);
    p1scatter_k<<<NBLK1, 512, 0, stream>>>(src, dst, bcur, bufA, E);
    p2sort_k<<<NBKT, 512, 0, stream>>>(bufA, bbase, srcs, dstS);
    off_k<<<(E + 511) / 512, 512, 0, stream>>>(dstS, off, N, E);

    const float* in = x;
    float* outs[3] = {hA, hB, (float*)d_out};
    const int node_blocks = (N + 3) / 4;
    const int aggr_blocks = 8 * ((N + 15) / 16);
    for (int l = 0; l < 3; ++l) {
        gemm_k<<<(N + 63) / 64, 256, 0, stream>>>(in, Wl[l], bl[l], aWl[l], zb, asrc, adst, N);
        alpha_k<<<node_blocks, 256, 0, stream>>>(asrc, adst, off, srcs, abl[l], pair, N);
        aggr_k<<<aggr_blocks, 256, 0, stream>>>(zb, pair, off, outs[l], N, (l < 2) ? 1 : 0);
        in = outs[l];
    }
}